// Round 3
// baseline (653.729 us; speedup 1.0000x reference)
//
#include <hip/hip_runtime.h>
#include <cstdint>
#include <cstddef>

// Problem constants (B=2, L=2048, D=1024, E=8, F=2048, TOP_K=2)
constexpr int T_TOK = 4096;      // B*L
constexpr int D_DIM = 1024;
constexpr int E_NUM = 8;
constexpr int F_DIM = 2048;
constexpr int C2F   = 4096;      // 2*F
constexpr int NPAIR = T_TOK * 2; // 8192 (token, slot) pairs

#define ALPHA_SW 1.702f
#define LIMIT_SW 9.0f

// ---------------- workspace layout (bytes) ----------------
constexpr size_t OFF_COUNTS  = 0;
constexpr size_t OFF_CURSOR  = 32;
constexpr size_t OFF_OFFSETS = 64;
constexpr size_t OFF_SEL     = 128;
constexpr size_t OFF_WTS     = OFF_SEL + (size_t)NPAIR * 4;      // 32896
constexpr size_t OFF_PAIRTS  = OFF_WTS + (size_t)NPAIR * 4;      // 65664
constexpr size_t OFF_FACT    = 98432;                            // f_act bf16 [8192][2048]
constexpr size_t SZ_FACT     = (size_t)NPAIR * F_DIM * 2;        // 33.55 MB
constexpr size_t OFF_XG      = OFF_FACT + SZ_FACT;               // xg bf16 [8192][1024]
// total ~50.4 MB

typedef __bf16 bf16x8 __attribute__((ext_vector_type(8)));
typedef float  f32x4  __attribute__((ext_vector_type(4)));

// round-half-up f32->bf16
__device__ __forceinline__ uint16_t bf16h(float f) {
  return (uint16_t)((__float_as_uint(f) + 0x8000u) >> 16);
}
__device__ __forceinline__ uint32_t pack2(float lo, float hi) {
  uint32_t ua = __float_as_uint(lo) + 0x8000u;
  uint32_t ub = __float_as_uint(hi) + 0x8000u;
  return __builtin_amdgcn_perm(ub, ua, 0x07060302); // {ub.hi16, ua.hi16}
}

// async global -> LDS, 16B per lane; lds dest = wave-uniform base + lane*16
__device__ __forceinline__ void gld_lds16(const uint16_t* g, uint16_t* l) {
  __builtin_amdgcn_global_load_lds(
      (const __attribute__((address_space(1))) unsigned int*)g,
      (__attribute__((address_space(3))) unsigned int*)l,
      16, 0, 0);
}

__device__ __forceinline__ float swiglu_f(float g, float v) {
  g = fminf(g, LIMIT_SW);
  v = fminf(fmaxf(v, -LIMIT_SW), LIMIT_SW);
  float s = 1.0f / (1.0f + expf(-ALPHA_SW * g));
  return g * s * (v + 1.0f);
}

// LDS tile: 128 rows x 32 bf16 (BK=32), row = 64B = 4 chunks of 16B.
// XOR swizzle: slot s of row r holds global k-chunk  s ^ ((r>>1)&3).
// -> reader bank-aliasing drops from 8-way to 2-way (free, m136).

// ---------------- K1: gate + top-2 + softmax + counts (fp64 routing) ----------------
__global__ __launch_bounds__(256) void gate_route_kernel(
    const float* __restrict__ x, const float* __restrict__ gate_w,
    int* __restrict__ sel, float* __restrict__ wts, int* __restrict__ counts) {
  int wave = threadIdx.x >> 6;
  int lane = threadIdx.x & 63;
  int t = blockIdx.x * 4 + wave;
  if (t >= T_TOK) return;

  double acc[E_NUM];
#pragma unroll
  for (int e = 0; e < E_NUM; ++e) acc[e] = 0.0;

  const float* xr = x + (size_t)t * D_DIM;
#pragma unroll 4
  for (int i = 0; i < D_DIM / 64; ++i) {
    int d = i * 64 + lane;
    float xv = xr[d];
    const float* gw = gate_w + (size_t)d * E_NUM;
    float4 ga = *(const float4*)gw;
    float4 gb = *(const float4*)(gw + 4);
    acc[0] += (double)xv * (double)ga.x;
    acc[1] += (double)xv * (double)ga.y;
    acc[2] += (double)xv * (double)ga.z;
    acc[3] += (double)xv * (double)ga.w;
    acc[4] += (double)xv * (double)gb.x;
    acc[5] += (double)xv * (double)gb.y;
    acc[6] += (double)xv * (double)gb.z;
    acc[7] += (double)xv * (double)gb.w;
  }
#pragma unroll
  for (int off = 32; off >= 1; off >>= 1) {
#pragma unroll
    for (int e = 0; e < E_NUM; ++e) acc[e] += __shfl_down(acc[e], off, 64);
  }
  if (lane == 0) {
    int b0 = 0;
#pragma unroll
    for (int e = 1; e < E_NUM; ++e)
      if (acc[e] > acc[b0]) b0 = e;
    int b1 = (b0 == 0) ? 1 : 0;
#pragma unroll
    for (int e = 0; e < E_NUM; ++e)
      if (e != b0 && acc[e] > acc[b1] && e != b1) {
        if (e < b1 && acc[e] == acc[b1]) continue;
        if (acc[e] > acc[b1]) b1 = e;
      }
    double p0 = 1.0 / (1.0 + exp(acc[b1] - acc[b0]));
    sel[t * 2 + 0] = b0;
    sel[t * 2 + 1] = b1;
    wts[t * 2 + 0] = (float)p0;
    wts[t * 2 + 1] = (float)(1.0 - p0);
    atomicAdd(&counts[b0], 1);
    atomicAdd(&counts[b1], 1);
  }
}

// ---------------- K2: exclusive prefix scan over 8 counts ----------------
__global__ void scan_kernel(const int* __restrict__ counts, int* __restrict__ offsets) {
  if (threadIdx.x == 0 && blockIdx.x == 0) {
    int s = 0;
    for (int e = 0; e < E_NUM; ++e) { offsets[e] = s; s += counts[e]; }
    offsets[E_NUM] = s;
  }
}

// ---------------- K3: scatter pairs into per-expert groups ----------------
__global__ __launch_bounds__(256) void scatter_kernel(
    const int* __restrict__ sel, const int* __restrict__ offsets,
    int* __restrict__ cursor, int* __restrict__ pair_ts) {
  int p = blockIdx.x * 256 + threadIdx.x;
  if (p >= NPAIR) return;
  int e = sel[p];
  int idx = offsets[e] + atomicAdd(&cursor[e], 1);
  pair_ts[idx] = p;
}

// ---------------- K4: gather x rows -> compacted bf16 ----------------
__global__ __launch_bounds__(256) void gather_x_kernel(
    const float* __restrict__ x, const int* __restrict__ pair_ts,
    uint16_t* __restrict__ xg) {
  int p = blockIdx.x;
  int t = pair_ts[p] >> 1;
  int d = threadIdx.x * 4;
  float4 v = *(const float4*)&x[(size_t)t * D_DIM + d];
  uint2 o;
  o.x = pack2(v.x, v.y);
  o.y = pack2(v.z, v.w);
  *(uint2*)&xg[(size_t)p * D_DIM + d] = o;
}

// ---------------- K5: GEMM1  f_act = swiglu(xg @ w1[e]^T + b1) ----------------
// 128x128 tile, BK=32, 4 waves (2x2), 4x4 MFMA accs/wave.
// A: bf16 xg via global_load_lds (source-swizzled). B: fp32 w1 inline-packed (dest-swizzled).
__global__ __launch_bounds__(256) void gemm1_kernel(
    const uint16_t* __restrict__ xg, const float* __restrict__ w1,
    const float* __restrict__ b1, const int* __restrict__ offsets,
    uint16_t* __restrict__ f_act) {
  const int e = blockIdx.z;
  const int base = offsets[e];
  const int n_e = offsets[e + 1] - base;
  const int row0 = blockIdx.y * 128;
  if (row0 >= n_e) return;
  const int c0 = blockIdx.x * 128;

  __shared__ uint16_t As[128 * 32];
  __shared__ uint16_t Bs[128 * 32];

  const int tid = threadIdx.x;
  const int lane = tid & 63;
  const int wv = tid >> 6;
  const int wm = wv & 1, wn = wv >> 1;

  // A staging: wave wv covers rows wv*16 + (lane>>2) (+64 for 2nd half); swizzled source chunk
  const int csw = ((lane & 3) ^ ((lane >> 3) & 3)) * 8;
  int ag0 = base + row0 + wv * 16 + (lane >> 2); if (ag0 > NPAIR - 1) ag0 = NPAIR - 1;
  int ag1 = ag0 + 64;                            if (ag1 > NPAIR - 1) ag1 = NPAIR - 1;
  const uint16_t* agp0 = xg + (size_t)ag0 * D_DIM + csw;
  const uint16_t* agp1 = xg + (size_t)ag1 * D_DIM + csw;
  uint16_t* alds0 = &As[(wv * 16) * 32];
  uint16_t* alds1 = &As[(64 + wv * 16) * 32];

  // B staging: thread covers rows (tid>>2) and (tid>>2)+64; natural source chunk, swizzled dest slot
  const float* bf0 = w1 + ((size_t)e * C2F + c0 + (tid >> 2)) * D_DIM + (tid & 3) * 8;
  const float* bf1 = bf0 + (size_t)64 * D_DIM;
  const int bsw = ((tid & 3) ^ ((tid >> 3) & 3)) * 8;
  uint16_t* bw0 = &Bs[(tid >> 2) * 32 + bsw];
  uint16_t* bw1 = &Bs[(64 + (tid >> 2)) * 32 + bsw];

  f32x4 acc[4][4];
#pragma unroll
  for (int mi = 0; mi < 4; ++mi)
#pragma unroll
    for (int ni = 0; ni < 4; ++ni) acc[mi][ni] = (f32x4){0.f, 0.f, 0.f, 0.f};

  const int ar = lane & 15;
  const int ak = ((lane >> 4) ^ ((lane >> 1) & 3)) * 8;  // un-swizzled reader slot

  for (int kk = 0; kk < D_DIM; kk += 32) {
    float4 x0 = *(const float4*)(bf0 + kk);
    float4 x1 = *(const float4*)(bf0 + kk + 4);
    float4 y0 = *(const float4*)(bf1 + kk);
    float4 y1 = *(const float4*)(bf1 + kk + 4);
    __syncthreads();  // previous iter's LDS reads complete
    gld_lds16(agp0 + kk, alds0);
    gld_lds16(agp1 + kk, alds1);
    uint4 p0, p1;
    p0.x = pack2(x0.x, x0.y); p0.y = pack2(x0.z, x0.w);
    p0.z = pack2(x1.x, x1.y); p0.w = pack2(x1.z, x1.w);
    p1.x = pack2(y0.x, y0.y); p1.y = pack2(y0.z, y0.w);
    p1.z = pack2(y1.x, y1.y); p1.w = pack2(y1.z, y1.w);
    *(uint4*)bw0 = p0;
    *(uint4*)bw1 = p1;
    __syncthreads();  // staging visible

    bf16x8 af[4], bfv[4];
#pragma unroll
    for (int mi = 0; mi < 4; ++mi)
      af[mi] = *(const bf16x8*)&As[(wm * 64 + mi * 16 + ar) * 32 + ak];
#pragma unroll
    for (int ni = 0; ni < 4; ++ni)
      bfv[ni] = *(const bf16x8*)&Bs[(wn * 64 + ni * 16 + ar) * 32 + ak];
#pragma unroll
    for (int mi = 0; mi < 4; ++mi)
#pragma unroll
      for (int ni = 0; ni < 4; ++ni)
        acc[mi][ni] = __builtin_amdgcn_mfma_f32_16x16x32_bf16(af[mi], bfv[ni], acc[mi][ni], 0, 0, 0);
  }

  // epilogue: bias + swiglu pairing via shfl_xor(1); even cols hold g, odd v
  const float* b1e = b1 + (size_t)e * C2F + c0;
#pragma unroll
  for (int ni = 0; ni < 4; ++ni) {
    int col_l = wn * 64 + ni * 16 + (lane & 15);
    float bias = b1e[col_l];
#pragma unroll
    for (int mi = 0; mi < 4; ++mi)
#pragma unroll
      for (int r = 0; r < 4; ++r) {
        float val = acc[mi][ni][r] + bias;
        float oth = __shfl_xor(val, 1);
        float g = (lane & 1) ? oth : val;
        float v = (lane & 1) ? val : oth;
        float f = swiglu_f(g, v);
        int row_l = wm * 64 + mi * 16 + (lane >> 4) * 4 + r;
        if (!(lane & 1) && (row0 + row_l) < n_e)
          f_act[(size_t)(base + row0 + row_l) * F_DIM + ((c0 + col_l) >> 1)] = bf16h(f);
      }
  }
}

// ---------------- K6: GEMM2  out[t] += wt * (f_act @ w2[e]^T + b2) ----------------
__global__ __launch_bounds__(256) void gemm2_kernel(
    const uint16_t* __restrict__ f_act, const float* __restrict__ w2,
    const float* __restrict__ b2, const int* __restrict__ offsets,
    const int* __restrict__ pair_ts, const float* __restrict__ wts,
    float* __restrict__ out) {
  const int e = blockIdx.z;
  const int base = offsets[e];
  const int n_e = offsets[e + 1] - base;
  const int row0 = blockIdx.y * 128;
  if (row0 >= n_e) return;
  const int c0 = blockIdx.x * 128;

  __shared__ uint16_t As[128 * 32];
  __shared__ uint16_t Bs[128 * 32];

  const int tid = threadIdx.x;
  const int lane = tid & 63;
  const int wv = tid >> 6;
  const int wm = wv & 1, wn = wv >> 1;

  const int csw = ((lane & 3) ^ ((lane >> 3) & 3)) * 8;
  int ag0 = base + row0 + wv * 16 + (lane >> 2); if (ag0 > NPAIR - 1) ag0 = NPAIR - 1;
  int ag1 = ag0 + 64;                            if (ag1 > NPAIR - 1) ag1 = NPAIR - 1;
  const uint16_t* agp0 = f_act + (size_t)ag0 * F_DIM + csw;
  const uint16_t* agp1 = f_act + (size_t)ag1 * F_DIM + csw;
  uint16_t* alds0 = &As[(wv * 16) * 32];
  uint16_t* alds1 = &As[(64 + wv * 16) * 32];

  const float* bf0 = w2 + ((size_t)e * D_DIM + c0 + (tid >> 2)) * F_DIM + (tid & 3) * 8;
  const float* bf1 = bf0 + (size_t)64 * F_DIM;
  const int bsw = ((tid & 3) ^ ((tid >> 3) & 3)) * 8;
  uint16_t* bw0 = &Bs[(tid >> 2) * 32 + bsw];
  uint16_t* bw1 = &Bs[(64 + (tid >> 2)) * 32 + bsw];

  f32x4 acc[4][4];
#pragma unroll
  for (int mi = 0; mi < 4; ++mi)
#pragma unroll
    for (int ni = 0; ni < 4; ++ni) acc[mi][ni] = (f32x4){0.f, 0.f, 0.f, 0.f};

  const int ar = lane & 15;
  const int ak = ((lane >> 4) ^ ((lane >> 1) & 3)) * 8;

  for (int kk = 0; kk < F_DIM; kk += 32) {
    float4 x0 = *(const float4*)(bf0 + kk);
    float4 x1 = *(const float4*)(bf0 + kk + 4);
    float4 y0 = *(const float4*)(bf1 + kk);
    float4 y1 = *(const float4*)(bf1 + kk + 4);
    __syncthreads();
    gld_lds16(agp0 + kk, alds0);
    gld_lds16(agp1 + kk, alds1);
    uint4 p0, p1;
    p0.x = pack2(x0.x, x0.y); p0.y = pack2(x0.z, x0.w);
    p0.z = pack2(x1.x, x1.y); p0.w = pack2(x1.z, x1.w);
    p1.x = pack2(y0.x, y0.y); p1.y = pack2(y0.z, y0.w);
    p1.z = pack2(y1.x, y1.y); p1.w = pack2(y1.z, y1.w);
    *(uint4*)bw0 = p0;
    *(uint4*)bw1 = p1;
    __syncthreads();

    bf16x8 af[4], bfv[4];
#pragma unroll
    for (int mi = 0; mi < 4; ++mi)
      af[mi] = *(const bf16x8*)&As[(wm * 64 + mi * 16 + ar) * 32 + ak];
#pragma unroll
    for (int ni = 0; ni < 4; ++ni)
      bfv[ni] = *(const bf16x8*)&Bs[(wn * 64 + ni * 16 + ar) * 32 + ak];
#pragma unroll
    for (int mi = 0; mi < 4; ++mi)
#pragma unroll
      for (int ni = 0; ni < 4; ++ni)
        acc[mi][ni] = __builtin_amdgcn_mfma_f32_16x16x32_bf16(af[mi], bfv[ni], acc[mi][ni], 0, 0, 0);
  }

  // epilogue: bias + weighted atomic scatter into out
  float bias4[4]; int d4a[4];
#pragma unroll
  for (int ni = 0; ni < 4; ++ni) {
    d4a[ni] = c0 + wn * 64 + ni * 16 + (lane & 15);
    bias4[ni] = b2[(size_t)e * D_DIM + d4a[ni]];
  }
#pragma unroll
  for (int mi = 0; mi < 4; ++mi)
#pragma unroll
    for (int r = 0; r < 4; ++r) {
      int grow = row0 + wm * 64 + mi * 16 + (lane >> 4) * 4 + r;
      if (grow >= n_e) continue;
      int pp = pair_ts[base + grow];
      float wt = wts[pp];
      size_t ob = (size_t)(pp >> 1) * D_DIM;
#pragma unroll
      for (int ni = 0; ni < 4; ++ni)
        atomicAdd(&out[ob + d4a[ni]], wt * (acc[mi][ni][r] + bias4[ni]));
    }
}

extern "C" void kernel_launch(void* const* d_in, const int* in_sizes, int n_in,
                              void* d_out, int out_size, void* d_ws, size_t ws_size,
                              hipStream_t stream) {
  const float* x      = (const float*)d_in[0];
  const float* gate_w = (const float*)d_in[1];
  const float* w1     = (const float*)d_in[2];
  const float* b1     = (const float*)d_in[3];
  const float* w2     = (const float*)d_in[4];
  const float* b2     = (const float*)d_in[5];
  float* out = (float*)d_out;

  char* ws = (char*)d_ws;
  int*      counts  = (int*)(ws + OFF_COUNTS);
  int*      cursor  = (int*)(ws + OFF_CURSOR);
  int*      offsets = (int*)(ws + OFF_OFFSETS);
  int*      sel     = (int*)(ws + OFF_SEL);
  float*    wts     = (float*)(ws + OFF_WTS);
  int*      pair_ts = (int*)(ws + OFF_PAIRTS);
  uint16_t* f_act   = (uint16_t*)(ws + OFF_FACT);
  uint16_t* xg      = (uint16_t*)(ws + OFF_XG);

  hipMemsetAsync(d_ws, 0, 64, stream);
  hipMemsetAsync(d_out, 0, (size_t)out_size * sizeof(float), stream);
  gate_route_kernel<<<T_TOK / 4, 256, 0, stream>>>(x, gate_w, sel, wts, counts);
  scan_kernel<<<1, 64, 0, stream>>>(counts, offsets);
  scatter_kernel<<<NPAIR / 256, 256, 0, stream>>>(sel, offsets, cursor, pair_ts);
  gather_x_kernel<<<NPAIR, 256, 0, stream>>>(x, pair_ts, xg);
  gemm1_kernel<<<dim3(C2F / 128, 64, E_NUM), 256, 0, stream>>>(xg, w1, b1, offsets, f_act);
  gemm2_kernel<<<dim3(D_DIM / 128, 64, E_NUM), 256, 0, stream>>>(f_act, w2, b2, offsets, pair_ts, wts, out);
}

// Round 4
// 589.740 us; speedup vs baseline: 1.1085x; 1.1085x over previous
//
#include <hip/hip_runtime.h>
#include <cstdint>
#include <cstddef>

// Problem constants (B=2, L=2048, D=1024, E=8, F=2048, TOP_K=2)
constexpr int T_TOK = 4096;      // B*L
constexpr int D_DIM = 1024;
constexpr int E_NUM = 8;
constexpr int F_DIM = 2048;
constexpr int C2F   = 4096;      // 2*F
constexpr int NPAIR = T_TOK * 2; // 8192 (token, slot) pairs

#define ALPHA_SW 1.702f
#define LIMIT_SW 9.0f

// ---------------- workspace layout (bytes) ----------------
constexpr size_t OFF_COUNTS  = 0;
constexpr size_t OFF_CURSOR  = 32;
constexpr size_t OFF_OFFSETS = 64;
constexpr size_t OFF_SEL     = 128;
constexpr size_t OFF_WTS     = OFF_SEL    + (size_t)NPAIR * 4;   // 32896
constexpr size_t OFF_PAIRTS  = OFF_WTS    + (size_t)NPAIR * 4;   // 65664
constexpr size_t OFF_POSOF   = OFF_PAIRTS + (size_t)NPAIR * 4;   // 98432
constexpr size_t OFF_FACT    = 131328;                           // f_act bf16 [8192][2048]
constexpr size_t SZ_FACT     = (size_t)NPAIR * F_DIM * 2;        // 33.55 MB
constexpr size_t OFF_XG      = OFF_FACT + SZ_FACT;               // xg bf16 [8192][1024]
constexpr size_t SZ_XG       = (size_t)NPAIR * D_DIM * 2;        // 16.78 MB
constexpr size_t OFF_WB      = OFF_XG + SZ_XG;                   // w1 bf16 (67.1 MB), later: w2 bf16 + y
constexpr size_t SZ_W1B      = (size_t)E_NUM * C2F * D_DIM * 2;  // 67.11 MB
constexpr size_t SZ_W2B      = (size_t)E_NUM * D_DIM * F_DIM * 2;// 33.55 MB
constexpr size_t OFF_Y       = OFF_WB + SZ_W2B;                  // y fp32 [8192][1024] overlays w1b tail
// end = OFF_WB + SZ_W1B = 117571840 B — proven available (R2 fast path ran: FETCH 107 MB)

typedef __bf16 bf16x8 __attribute__((ext_vector_type(8)));
typedef float  f32x4  __attribute__((ext_vector_type(4)));

// round-half-up f32->bf16
__device__ __forceinline__ uint16_t bf16h(float f) {
  return (uint16_t)((__float_as_uint(f) + 0x8000u) >> 16);
}
__device__ __forceinline__ uint32_t pack2(float lo, float hi) {
  uint32_t ua = __float_as_uint(lo) + 0x8000u;
  uint32_t ub = __float_as_uint(hi) + 0x8000u;
  return __builtin_amdgcn_perm(ub, ua, 0x07060302); // {ub.hi16, ua.hi16}
}

// async global -> LDS, 16B per lane; lds dest = wave-uniform base + lane*16
__device__ __forceinline__ void gld_lds16(const uint16_t* g, uint16_t* l) {
  __builtin_amdgcn_global_load_lds(
      (const __attribute__((address_space(1))) unsigned int*)g,
      (__attribute__((address_space(3))) unsigned int*)l,
      16, 0, 0);
}

__device__ __forceinline__ float swiglu_f(float g, float v) {
  g = fminf(g, LIMIT_SW);
  v = fminf(fmaxf(v, -LIMIT_SW), LIMIT_SW);
  float s = 1.0f / (1.0f + expf(-ALPHA_SW * g));
  return g * s * (v + 1.0f);
}

// LDS tile: 128 rows x 32 bf16 (BK=32); row = 64B = 4 chunks of 16B.
// XOR swizzle: slot s of row r holds global k-chunk s ^ ((r>>1)&3).
// Staging via global_load_lds: permute SOURCE chunk per lane (dest stays lane*16).
// Reader un-swizzle folds into lane-constant ak. Measured: conflicts 8.78M -> 0 (R3).

// ---------------- K1: gate + top-2 + softmax + counts (fp64 routing) ----------------
__global__ __launch_bounds__(256) void gate_route_kernel(
    const float* __restrict__ x, const float* __restrict__ gate_w,
    int* __restrict__ sel, float* __restrict__ wts, int* __restrict__ counts) {
  int wave = threadIdx.x >> 6;
  int lane = threadIdx.x & 63;
  int t = blockIdx.x * 4 + wave;
  if (t >= T_TOK) return;

  double acc[E_NUM];
#pragma unroll
  for (int e = 0; e < E_NUM; ++e) acc[e] = 0.0;

  const float* xr = x + (size_t)t * D_DIM;
#pragma unroll 4
  for (int i = 0; i < D_DIM / 64; ++i) {
    int d = i * 64 + lane;
    float xv = xr[d];
    const float* gw = gate_w + (size_t)d * E_NUM;
    float4 ga = *(const float4*)gw;
    float4 gb = *(const float4*)(gw + 4);
    acc[0] += (double)xv * (double)ga.x;
    acc[1] += (double)xv * (double)ga.y;
    acc[2] += (double)xv * (double)ga.z;
    acc[3] += (double)xv * (double)ga.w;
    acc[4] += (double)xv * (double)gb.x;
    acc[5] += (double)xv * (double)gb.y;
    acc[6] += (double)xv * (double)gb.z;
    acc[7] += (double)xv * (double)gb.w;
  }
#pragma unroll
  for (int off = 32; off >= 1; off >>= 1) {
#pragma unroll
    for (int e = 0; e < E_NUM; ++e) acc[e] += __shfl_down(acc[e], off, 64);
  }
  if (lane == 0) {
    int b0 = 0;
#pragma unroll
    for (int e = 1; e < E_NUM; ++e)
      if (acc[e] > acc[b0]) b0 = e;
    int b1 = (b0 == 0) ? 1 : 0;
#pragma unroll
    for (int e = 0; e < E_NUM; ++e)
      if (e != b0 && acc[e] > acc[b1] && e != b1) {
        if (e < b1 && acc[e] == acc[b1]) continue;
        if (acc[e] > acc[b1]) b1 = e;
      }
    double p0 = 1.0 / (1.0 + exp(acc[b1] - acc[b0]));
    sel[t * 2 + 0] = b0;
    sel[t * 2 + 1] = b1;
    wts[t * 2 + 0] = (float)p0;
    wts[t * 2 + 1] = (float)(1.0 - p0);
    atomicAdd(&counts[b0], 1);
    atomicAdd(&counts[b1], 1);
  }
}

// ---------------- K2: exclusive prefix scan over 8 counts ----------------
__global__ void scan_kernel(const int* __restrict__ counts, int* __restrict__ offsets) {
  if (threadIdx.x == 0 && blockIdx.x == 0) {
    int s = 0;
    for (int e = 0; e < E_NUM; ++e) { offsets[e] = s; s += counts[e]; }
    offsets[E_NUM] = s;
  }
}

// ---------------- K3: scatter pairs into per-expert groups (+ inverse map) ----------------
__global__ __launch_bounds__(256) void scatter_kernel(
    const int* __restrict__ sel, const int* __restrict__ offsets,
    int* __restrict__ cursor, int* __restrict__ pair_ts, int* __restrict__ pos_of) {
  int p = blockIdx.x * 256 + threadIdx.x;
  if (p >= NPAIR) return;
  int e = sel[p];
  int idx = offsets[e] + atomicAdd(&cursor[e], 1);
  pair_ts[idx] = p;
  pos_of[p] = idx;
}

// ---------------- K4: gather x rows -> compacted bf16 ----------------
__global__ __launch_bounds__(256) void gather_x_kernel(
    const float* __restrict__ x, const int* __restrict__ pair_ts,
    uint16_t* __restrict__ xg) {
  int p = blockIdx.x;
  int t = pair_ts[p] >> 1;
  int d = threadIdx.x * 4;
  float4 v = *(const float4*)&x[(size_t)t * D_DIM + d];
  uint2 o;
  o.x = pack2(v.x, v.y);
  o.y = pack2(v.z, v.w);
  *(uint2*)&xg[(size_t)p * D_DIM + d] = o;
}

// ---------------- K5: f32 -> bf16 bulk convert ----------------
__global__ __launch_bounds__(256) void cvt_bf16_kernel(
    const float* __restrict__ src, uint16_t* __restrict__ dst, int n4) {
  int i = blockIdx.x * 256 + threadIdx.x;
  if (i >= n4) return;
  float4 v = ((const float4*)src)[i];
  uint2 o;
  o.x = pack2(v.x, v.y);
  o.y = pack2(v.z, v.w);
  ((uint2*)dst)[i] = o;
}

// ---------------- K6: GEMM1  f_act = swiglu(xg @ w1b^T + b1) ----------------
// 128x128 tile, BK=32, 4 waves (2x2), 4x4 MFMA accs/wave. All-async swizzled staging.
__global__ __launch_bounds__(256) void gemm1_kernel(
    const uint16_t* __restrict__ xg, const uint16_t* __restrict__ w1b,
    const float* __restrict__ b1, const int* __restrict__ offsets,
    uint16_t* __restrict__ f_act) {
  const int e = blockIdx.z;
  const int base = offsets[e];
  const int n_e = offsets[e + 1] - base;
  const int row0 = blockIdx.y * 128;
  if (row0 >= n_e) return;
  const int c0 = blockIdx.x * 128;

  __shared__ uint16_t As[128 * 32];
  __shared__ uint16_t Bs[128 * 32];

  const int tid = threadIdx.x;
  const int lane = tid & 63;
  const int wv = tid >> 6;
  const int wm = wv & 1, wn = wv >> 1;

  // source-swizzled chunk offset (elements)
  const int csw = ((lane & 3) ^ ((lane >> 3) & 3)) * 8;

  int ag0 = base + row0 + wv * 16 + (lane >> 2); if (ag0 > NPAIR - 1) ag0 = NPAIR - 1;
  int ag1 = ag0 + 64;                            if (ag1 > NPAIR - 1) ag1 = NPAIR - 1;
  const uint16_t* agp0 = xg + (size_t)ag0 * D_DIM + csw;
  const uint16_t* agp1 = xg + (size_t)ag1 * D_DIM + csw;
  uint16_t* alds0 = &As[(wv * 16) * 32];
  uint16_t* alds1 = &As[(64 + wv * 16) * 32];

  const uint16_t* bgp0 = w1b + ((size_t)e * C2F + c0 + wv * 16 + (lane >> 2)) * D_DIM + csw;
  const uint16_t* bgp1 = bgp0 + (size_t)64 * D_DIM;
  uint16_t* blds0 = &Bs[(wv * 16) * 32];
  uint16_t* blds1 = &Bs[(64 + wv * 16) * 32];

  f32x4 acc[4][4];
#pragma unroll
  for (int mi = 0; mi < 4; ++mi)
#pragma unroll
    for (int ni = 0; ni < 4; ++ni) acc[mi][ni] = (f32x4){0.f, 0.f, 0.f, 0.f};

  const int ar = lane & 15;
  const int ak = ((lane >> 4) ^ ((lane >> 1) & 3)) * 8;  // un-swizzled reader slot

  for (int kk = 0; kk < D_DIM; kk += 32) {
    __syncthreads();  // prior iter's ds_reads done
    gld_lds16(agp0 + kk, alds0);
    gld_lds16(agp1 + kk, alds1);
    gld_lds16(bgp0 + kk, blds0);
    gld_lds16(bgp1 + kk, blds1);
    __syncthreads();  // staging visible (vmcnt drained by barrier)

    bf16x8 af[4], bfv[4];
#pragma unroll
    for (int mi = 0; mi < 4; ++mi)
      af[mi] = *(const bf16x8*)&As[(wm * 64 + mi * 16 + ar) * 32 + ak];
#pragma unroll
    for (int ni = 0; ni < 4; ++ni)
      bfv[ni] = *(const bf16x8*)&Bs[(wn * 64 + ni * 16 + ar) * 32 + ak];
#pragma unroll
    for (int mi = 0; mi < 4; ++mi)
#pragma unroll
      for (int ni = 0; ni < 4; ++ni)
        acc[mi][ni] = __builtin_amdgcn_mfma_f32_16x16x32_bf16(af[mi], bfv[ni], acc[mi][ni], 0, 0, 0);
  }

  // epilogue: bias + swiglu pairing via shfl_xor(1); even cols hold g, odd v
  const float* b1e = b1 + (size_t)e * C2F + c0;
#pragma unroll
  for (int ni = 0; ni < 4; ++ni) {
    int col_l = wn * 64 + ni * 16 + (lane & 15);
    float bias = b1e[col_l];
#pragma unroll
    for (int mi = 0; mi < 4; ++mi)
#pragma unroll
      for (int r = 0; r < 4; ++r) {
        float val = acc[mi][ni][r] + bias;
        float oth = __shfl_xor(val, 1);
        float g = (lane & 1) ? oth : val;
        float v = (lane & 1) ? val : oth;
        float f = swiglu_f(g, v);
        int row_l = wm * 64 + mi * 16 + (lane >> 4) * 4 + r;
        if (!(lane & 1) && (row0 + row_l) < n_e)
          f_act[(size_t)(base + row0 + row_l) * F_DIM + ((c0 + col_l) >> 1)] = bf16h(f);
      }
  }
}

// ---------------- K7: GEMM2  y = f_act @ w2b^T + b2  (plain stores, no atomics) ----------------
__global__ __launch_bounds__(256) void gemm2_kernel(
    const uint16_t* __restrict__ f_act, const uint16_t* __restrict__ w2b,
    const float* __restrict__ b2, const int* __restrict__ offsets,
    float* __restrict__ y) {
  const int e = blockIdx.z;
  const int base = offsets[e];
  const int n_e = offsets[e + 1] - base;
  const int row0 = blockIdx.y * 128;
  if (row0 >= n_e) return;
  const int c0 = blockIdx.x * 128;

  __shared__ uint16_t As[128 * 32];
  __shared__ uint16_t Bs[128 * 32];

  const int tid = threadIdx.x;
  const int lane = tid & 63;
  const int wv = tid >> 6;
  const int wm = wv & 1, wn = wv >> 1;

  const int csw = ((lane & 3) ^ ((lane >> 3) & 3)) * 8;

  int ag0 = base + row0 + wv * 16 + (lane >> 2); if (ag0 > NPAIR - 1) ag0 = NPAIR - 1;
  int ag1 = ag0 + 64;                            if (ag1 > NPAIR - 1) ag1 = NPAIR - 1;
  const uint16_t* agp0 = f_act + (size_t)ag0 * F_DIM + csw;
  const uint16_t* agp1 = f_act + (size_t)ag1 * F_DIM + csw;
  uint16_t* alds0 = &As[(wv * 16) * 32];
  uint16_t* alds1 = &As[(64 + wv * 16) * 32];

  const uint16_t* bgp0 = w2b + ((size_t)e * D_DIM + c0 + wv * 16 + (lane >> 2)) * F_DIM + csw;
  const uint16_t* bgp1 = bgp0 + (size_t)64 * F_DIM;
  uint16_t* blds0 = &Bs[(wv * 16) * 32];
  uint16_t* blds1 = &Bs[(64 + wv * 16) * 32];

  f32x4 acc[4][4];
#pragma unroll
  for (int mi = 0; mi < 4; ++mi)
#pragma unroll
    for (int ni = 0; ni < 4; ++ni) acc[mi][ni] = (f32x4){0.f, 0.f, 0.f, 0.f};

  const int ar = lane & 15;
  const int ak = ((lane >> 4) ^ ((lane >> 1) & 3)) * 8;

  for (int kk = 0; kk < F_DIM; kk += 32) {
    __syncthreads();
    gld_lds16(agp0 + kk, alds0);
    gld_lds16(agp1 + kk, alds1);
    gld_lds16(bgp0 + kk, blds0);
    gld_lds16(bgp1 + kk, blds1);
    __syncthreads();

    bf16x8 af[4], bfv[4];
#pragma unroll
    for (int mi = 0; mi < 4; ++mi)
      af[mi] = *(const bf16x8*)&As[(wm * 64 + mi * 16 + ar) * 32 + ak];
#pragma unroll
    for (int ni = 0; ni < 4; ++ni)
      bfv[ni] = *(const bf16x8*)&Bs[(wn * 64 + ni * 16 + ar) * 32 + ak];
#pragma unroll
    for (int mi = 0; mi < 4; ++mi)
#pragma unroll
      for (int ni = 0; ni < 4; ++ni)
        acc[mi][ni] = __builtin_amdgcn_mfma_f32_16x16x32_bf16(af[mi], bfv[ni], acc[mi][ni], 0, 0, 0);
  }

  // epilogue: bias + direct store into compacted y (16 lanes -> 64B contiguous)
  float bias4[4]; int d4a[4];
#pragma unroll
  for (int ni = 0; ni < 4; ++ni) {
    d4a[ni] = c0 + wn * 64 + ni * 16 + (lane & 15);
    bias4[ni] = b2[(size_t)e * D_DIM + d4a[ni]];
  }
#pragma unroll
  for (int mi = 0; mi < 4; ++mi)
#pragma unroll
    for (int r = 0; r < 4; ++r) {
      int grow = row0 + wm * 64 + mi * 16 + (lane >> 4) * 4 + r;
      if (grow >= n_e) continue;
      size_t yb = (size_t)(base + grow) * D_DIM;
#pragma unroll
      for (int ni = 0; ni < 4; ++ni)
        y[yb + d4a[ni]] = acc[mi][ni][r] + bias4[ni];
    }
}

// ---------------- K8: combine the two expert outputs per token ----------------
__global__ __launch_bounds__(256) void combine_kernel(
    const float* __restrict__ y, const int* __restrict__ pos_of,
    const float* __restrict__ wts, float* __restrict__ out) {
  int t = blockIdx.x;
  int d4 = threadIdx.x * 4;  // 256 threads x 4 = 1024 cols
  int p0 = pos_of[t * 2], p1 = pos_of[t * 2 + 1];
  float w0 = wts[t * 2], w1v = wts[t * 2 + 1];
  float4 a = *(const float4*)&y[(size_t)p0 * D_DIM + d4];
  float4 b = *(const float4*)&y[(size_t)p1 * D_DIM + d4];
  float4 o;
  o.x = w0 * a.x + w1v * b.x;
  o.y = w0 * a.y + w1v * b.y;
  o.z = w0 * a.z + w1v * b.z;
  o.w = w0 * a.w + w1v * b.w;
  *(float4*)&out[(size_t)t * D_DIM + d4] = o;
}

extern "C" void kernel_launch(void* const* d_in, const int* in_sizes, int n_in,
                              void* d_out, int out_size, void* d_ws, size_t ws_size,
                              hipStream_t stream) {
  const float* x      = (const float*)d_in[0];
  const float* gate_w = (const float*)d_in[1];
  const float* w1     = (const float*)d_in[2];
  const float* b1     = (const float*)d_in[3];
  const float* w2     = (const float*)d_in[4];
  const float* b2     = (const float*)d_in[5];
  float* out = (float*)d_out;

  char* ws = (char*)d_ws;
  int*      counts  = (int*)(ws + OFF_COUNTS);
  int*      cursor  = (int*)(ws + OFF_CURSOR);
  int*      offsets = (int*)(ws + OFF_OFFSETS);
  int*      sel     = (int*)(ws + OFF_SEL);
  float*    wts     = (float*)(ws + OFF_WTS);
  int*      pair_ts = (int*)(ws + OFF_PAIRTS);
  int*      pos_of  = (int*)(ws + OFF_POSOF);
  uint16_t* f_act   = (uint16_t*)(ws + OFF_FACT);
  uint16_t* xg      = (uint16_t*)(ws + OFF_XG);
  uint16_t* w1b     = (uint16_t*)(ws + OFF_WB);
  uint16_t* w2b     = (uint16_t*)(ws + OFF_WB);   // reuses w1b region after gemm1
  float*    yb      = (float*)(ws + OFF_Y);       // overlays w1b tail

  hipMemsetAsync(d_ws, 0, 64, stream);  // counts + cursor
  gate_route_kernel<<<T_TOK / 4, 256, 0, stream>>>(x, gate_w, sel, wts, counts);
  scan_kernel<<<1, 64, 0, stream>>>(counts, offsets);
  scatter_kernel<<<NPAIR / 256, 256, 0, stream>>>(sel, offsets, cursor, pair_ts, pos_of);
  gather_x_kernel<<<NPAIR, 256, 0, stream>>>(x, pair_ts, xg);
  cvt_bf16_kernel<<<(E_NUM * C2F * D_DIM / 4) / 256, 256, 0, stream>>>(
      w1, w1b, E_NUM * C2F * D_DIM / 4);
  gemm1_kernel<<<dim3(C2F / 128, 64, E_NUM), 256, 0, stream>>>(xg, w1b, b1, offsets, f_act);
  cvt_bf16_kernel<<<(E_NUM * D_DIM * F_DIM / 4) / 256, 256, 0, stream>>>(
      w2, w2b, E_NUM * D_DIM * F_DIM / 4);
  gemm2_kernel<<<dim3(D_DIM / 128, 64, E_NUM), 256, 0, stream>>>(f_act, w2b, b2, offsets, yb);
  combine_kernel<<<T_TOK, 256, 0, stream>>>(yb, pos_of, wts, out);
}